// Round 1
// baseline (247.095 us; speedup 1.0000x reference)
//
#include <hip/hip_runtime.h>

#define N_B 4
#define SEQ 2048
#define NH 8
#define HD 64
#define DM 512

typedef __attribute__((ext_vector_type(8))) short bf16x8;
typedef __attribute__((ext_vector_type(4))) float f32x4;

__device__ __forceinline__ unsigned short f2b(float f) {
  unsigned int u = __float_as_uint(f);
  u += 0x7FFFu + ((u >> 16) & 1u);  // RNE
  return (unsigned short)(u >> 16);
}
__device__ __forceinline__ float b2f(unsigned short s) {
  return __uint_as_float(((unsigned int)s) << 16);
}
__device__ __forceinline__ f32x4 mfma16(bf16x8 a, bf16x8 b, f32x4 c) {
  return __builtin_amdgcn_mfma_f32_16x16x32_bf16(a, b, c, 0, 0, 0);
}
__device__ __forceinline__ bf16x8 cvt8(const float* p) {
  float4 x = *(const float4*)p;
  float4 y = *(const float4*)(p + 4);
  bf16x8 r;
  r[0] = (short)f2b(x.x); r[1] = (short)f2b(x.y); r[2] = (short)f2b(x.z); r[3] = (short)f2b(x.w);
  r[4] = (short)f2b(y.x); r[5] = (short)f2b(y.y); r[6] = (short)f2b(y.z); r[7] = (short)f2b(y.w);
  return r;
}

// ---------------- projections: out = X @ W^T, per (n,h,tensor) ----------------
__global__ __launch_bounds__(256) void proj_kernel(
    const float* __restrict__ qin, const float* __restrict__ kin, const float* __restrict__ vin,
    const float* __restrict__ Wq, const float* __restrict__ Wk, const float* __restrict__ Wv,
    unsigned short* __restrict__ Qp, unsigned short* __restrict__ Kp, unsigned short* __restrict__ Vp)
{
  __shared__ __align__(16) unsigned short Wl[64][72];
  const int tid = threadIdx.x;
  const int lane = tid & 63;
  const int w = tid >> 6;
  const int z = blockIdx.z;
  const int nh = blockIdx.y;
  const int n = nh >> 3, h = nh & 7;
  const float* in = (z == 0) ? qin : (z == 1 ? kin : vin);
  const float* W  = (z == 0) ? Wq  : (z == 1 ? Wk  : Wv);

  for (int i = tid; i < 4096; i += 256)
    Wl[i >> 6][i & 63] = f2b(W[i]);
  __syncthreads();

  const int hi = lane >> 4, lo = lane & 15;
  const int srow = blockIdx.x * 64 + w * 16 + lo;
  const float* src = in + ((size_t)(n * SEQ + srow)) * DM + h * HD + hi * 8;
  bf16x8 a0 = cvt8(src);
  bf16x8 a1 = cvt8(src + 32);

  f32x4 acc[4];
  #pragma unroll
  for (int t = 0; t < 4; ++t) acc[t] = (f32x4){0.f, 0.f, 0.f, 0.f};
  #pragma unroll
  for (int t = 0; t < 4; ++t) {
    bf16x8 b0 = *(const bf16x8*)&Wl[t * 16 + lo][hi * 8];
    bf16x8 b1 = *(const bf16x8*)&Wl[t * 16 + lo][32 + hi * 8];
    acc[t] = mfma16(a0, b0, acc[t]);
    acc[t] = mfma16(a1, b1, acc[t]);
  }

  const int rbase = blockIdx.x * 64 + w * 16 + hi * 4;
  if (z < 2) {
    unsigned short* outp = (z == 0) ? Qp : Kp;
    #pragma unroll
    for (int t = 0; t < 4; ++t)
      #pragma unroll
      for (int j = 0; j < 4; ++j)
        outp[((size_t)(nh * SEQ + rbase + j)) * HD + t * 16 + lo] = f2b(acc[t][j]);
  } else {
    // V stored transposed: Vp[(nh*64 + d) * SEQ + s]
    #pragma unroll
    for (int t = 0; t < 4; ++t) {
      ushort4 v4;
      v4.x = f2b(acc[t][0]); v4.y = f2b(acc[t][1]);
      v4.z = f2b(acc[t][2]); v4.w = f2b(acc[t][3]);
      *(ushort4*)&Vp[((size_t)(nh * HD + t * 16 + lo)) * SEQ + rbase] = v4;
    }
  }
}

// ---------------- flash attention: per (n,h), 64 q-rows per block ----------------
__global__ __launch_bounds__(256) void attn_kernel(
    const unsigned short* __restrict__ Qp, const unsigned short* __restrict__ Kp,
    const unsigned short* __restrict__ Vp, const int* __restrict__ mask,
    unsigned short* __restrict__ AO)
{
  __shared__ __align__(16) unsigned short Kl[64][72];
  __shared__ __align__(16) unsigned short Vt[64][72];   // Vt[d][key] (from transposed Vp)
  __shared__ __align__(16) unsigned short Pl[4][16][72];
  __shared__ float maskf[64];

  const int tid = threadIdx.x, lane = tid & 63, w = tid >> 6;
  const int hi = lane >> 4, lo = lane & 15;
  const int nh = blockIdx.y, n = nh >> 3, h = nh & 7;
  const int qbase = blockIdx.x * 64 + w * 16;

  const unsigned short* qsrc = Qp + ((size_t)(nh * SEQ + qbase + lo)) * HD + hi * 8;
  bf16x8 qa0 = *(const bf16x8*)qsrc;
  bf16x8 qa1 = *(const bf16x8*)(qsrc + 32);

  f32x4 o[4];
  #pragma unroll
  for (int t = 0; t < 4; ++t) o[t] = (f32x4){0.f, 0.f, 0.f, 0.f};
  float m[4], l[4];
  #pragma unroll
  for (int j = 0; j < 4; ++j) { m[j] = -1e30f; l[j] = 0.f; }

  const int srow = tid >> 2, scol = (tid & 3) * 16;
  const unsigned short* kbp = Kp + ((size_t)nh * SEQ) * HD;
  const unsigned short* vbp = Vp + ((size_t)(nh * HD + srow)) * SEQ;

  for (int kv = 0; kv < SEQ / 64; ++kv) {
    const int kb = kv * 64;
    {
      const unsigned short* kp = kbp + (size_t)(kb + srow) * HD + scol;
      *(bf16x8*)&Kl[srow][scol]     = *(const bf16x8*)kp;
      *(bf16x8*)&Kl[srow][scol + 8] = *(const bf16x8*)(kp + 8);
      const unsigned short* vp = vbp + kb + scol;
      *(bf16x8*)&Vt[srow][scol]     = *(const bf16x8*)vp;
      *(bf16x8*)&Vt[srow][scol + 8] = *(const bf16x8*)(vp + 8);
      if (tid < 64) maskf[tid] = mask[n * SEQ + kb + tid] ? 0.f : -1e30f;
    }
    __syncthreads();

    // S = Q K^T for this wave's 16 rows x 64 keys
    f32x4 s[4];
    #pragma unroll
    for (int t = 0; t < 4; ++t) {
      s[t] = (f32x4){0.f, 0.f, 0.f, 0.f};
      bf16x8 b0 = *(const bf16x8*)&Kl[t * 16 + lo][hi * 8];
      bf16x8 b1 = *(const bf16x8*)&Kl[t * 16 + lo][32 + hi * 8];
      s[t] = mfma16(qa0, b0, s[t]);
      s[t] = mfma16(qa1, b1, s[t]);
    }
    float mb[4];
    #pragma unroll
    for (int t = 0; t < 4; ++t) mb[t] = maskf[t * 16 + lo];
    #pragma unroll
    for (int t = 0; t < 4; ++t)
      #pragma unroll
      for (int j = 0; j < 4; ++j)
        s[t][j] = s[t][j] * 0.125f + mb[t];   // scale then mask-bias (-1e30)

    float sc[4];
    #pragma unroll
    for (int j = 0; j < 4; ++j) {
      float rm = fmaxf(fmaxf(s[0][j], s[1][j]), fmaxf(s[2][j], s[3][j]));
      #pragma unroll
      for (int off = 1; off < 16; off <<= 1)
        rm = fmaxf(rm, __shfl_xor(rm, off));
      float nm = fmaxf(m[j], rm);
      sc[j] = __expf(m[j] - nm);
      m[j] = nm;
    }
    unsigned short pb[4][4];
    float rs[4] = {0.f, 0.f, 0.f, 0.f};
    #pragma unroll
    for (int t = 0; t < 4; ++t)
      #pragma unroll
      for (int j = 0; j < 4; ++j) {
        float p = __expf(s[t][j] - m[j]);
        unsigned short pbv = f2b(p);
        pb[t][j] = pbv;
        rs[j] += b2f(pbv);    // sum the rounded values for consistency with PV
      }
    #pragma unroll
    for (int j = 0; j < 4; ++j) {
      #pragma unroll
      for (int off = 1; off < 16; off <<= 1)
        rs[j] += __shfl_xor(rs[j], off);
      l[j] = l[j] * sc[j] + rs[j];
    }
    #pragma unroll
    for (int t = 0; t < 4; ++t)
      #pragma unroll
      for (int j = 0; j < 4; ++j)
        o[t][j] *= sc[j];

    // P -> per-wave LDS (row-major) -> A-fragments
    #pragma unroll
    for (int t = 0; t < 4; ++t)
      #pragma unroll
      for (int j = 0; j < 4; ++j)
        Pl[w][hi * 4 + j][t * 16 + lo] = pb[t][j];
    __asm__ volatile("s_waitcnt lgkmcnt(0)" ::: "memory");

    bf16x8 pa0 = *(const bf16x8*)&Pl[w][lo][hi * 8];
    bf16x8 pa1 = *(const bf16x8*)&Pl[w][lo][32 + hi * 8];
    #pragma unroll
    for (int t = 0; t < 4; ++t) {
      bf16x8 b0 = *(const bf16x8*)&Vt[t * 16 + lo][hi * 8];
      bf16x8 b1 = *(const bf16x8*)&Vt[t * 16 + lo][32 + hi * 8];
      o[t] = mfma16(pa0, b0, o[t]);
      o[t] = mfma16(pa1, b1, o[t]);
    }
    __syncthreads();
  }

  float rl[4];
  #pragma unroll
  for (int j = 0; j < 4; ++j) rl[j] = 1.f / l[j];
  #pragma unroll
  for (int t = 0; t < 4; ++t)
    #pragma unroll
    for (int j = 0; j < 4; ++j)
      AO[((size_t)(n * SEQ + qbase + hi * 4 + j)) * DM + h * HD + t * 16 + lo] =
          f2b(o[t][j] * rl[j]);
}

// ---------------- FC: out = AO @ Wfc^T + bfc ----------------
__global__ __launch_bounds__(256) void fc_kernel(
    const unsigned short* __restrict__ AO, const float* __restrict__ Wfc,
    const float* __restrict__ bfc, float* __restrict__ out)
{
  __shared__ __align__(16) unsigned short Al[64][72];
  __shared__ __align__(16) unsigned short Bl[64][72];
  const int tid = threadIdx.x, lane = tid & 63, w = tid >> 6;
  const int hi = lane >> 4, lo = lane & 15;
  const int rb = blockIdx.x * 64;
  const int cb = blockIdx.y * 64;
  const int srow = tid >> 2, scol = (tid & 3) * 16;

  f32x4 acc[4];
  #pragma unroll
  for (int t = 0; t < 4; ++t) acc[t] = (f32x4){0.f, 0.f, 0.f, 0.f};

  for (int kb = 0; kb < DM; kb += 64) {
    {
      const unsigned short* ap = AO + (size_t)(rb + srow) * DM + kb + scol;
      *(bf16x8*)&Al[srow][scol]     = *(const bf16x8*)ap;
      *(bf16x8*)&Al[srow][scol + 8] = *(const bf16x8*)(ap + 8);
      const float* wp = Wfc + (size_t)(cb + srow) * DM + kb + scol;
      *(bf16x8*)&Bl[srow][scol]     = cvt8(wp);
      *(bf16x8*)&Bl[srow][scol + 8] = cvt8(wp + 8);
    }
    __syncthreads();
    bf16x8 a0 = *(const bf16x8*)&Al[w * 16 + lo][hi * 8];
    bf16x8 a1 = *(const bf16x8*)&Al[w * 16 + lo][32 + hi * 8];
    #pragma unroll
    for (int t = 0; t < 4; ++t) {
      bf16x8 b0 = *(const bf16x8*)&Bl[t * 16 + lo][hi * 8];
      bf16x8 b1 = *(const bf16x8*)&Bl[t * 16 + lo][32 + hi * 8];
      acc[t] = mfma16(a0, b0, acc[t]);
      acc[t] = mfma16(a1, b1, acc[t]);
    }
    __syncthreads();
  }

  #pragma unroll
  for (int t = 0; t < 4; ++t) {
    float bias = bfc[cb + t * 16 + lo];
    #pragma unroll
    for (int j = 0; j < 4; ++j)
      out[(size_t)(rb + w * 16 + hi * 4 + j) * DM + cb + t * 16 + lo] = acc[t][j] + bias;
  }
}

extern "C" void kernel_launch(void* const* d_in, const int* in_sizes, int n_in,
                              void* d_out, int out_size, void* d_ws, size_t ws_size,
                              hipStream_t stream) {
  const float* value = (const float*)d_in[0];
  const float* key   = (const float*)d_in[1];
  const float* query = (const float*)d_in[2];
  const int*   mask  = (const int*)d_in[3];
  const float* Wv    = (const float*)d_in[4];
  const float* Wk    = (const float*)d_in[5];
  const float* Wq    = (const float*)d_in[6];
  const float* Wfc   = (const float*)d_in[7];
  const float* bfc   = (const float*)d_in[8];
  float* out = (float*)d_out;

  const size_t per = (size_t)N_B * NH * SEQ * HD;  // 4,194,304 elements
  unsigned short* Qp = (unsigned short*)d_ws;
  unsigned short* Kp = Qp + per;
  unsigned short* Vp = Kp + per;
  unsigned short* AO = Vp + per;

  proj_kernel<<<dim3(SEQ / 64, N_B * NH, 3), 256, 0, stream>>>(
      query, key, value, Wq, Wk, Wv, Qp, Kp, Vp);
  attn_kernel<<<dim3(SEQ / 64, N_B * NH), 256, 0, stream>>>(Qp, Kp, Vp, mask, AO);
  fc_kernel<<<dim3(N_B * SEQ / 64, DM / 64), 256, 0, stream>>>(AO, Wfc, bfc, out);
}

// Round 3
// 222.831 us; speedup vs baseline: 1.1089x; 1.1089x over previous
//
#include <hip/hip_runtime.h>

#define N_B 4
#define SEQ 2048
#define NH 8
#define HD 64
#define DM 512

typedef __attribute__((ext_vector_type(8))) short bf16x8;
typedef __attribute__((ext_vector_type(4))) short bf16x4;
typedef __attribute__((ext_vector_type(4))) float f32x4;

__device__ __forceinline__ unsigned short f2b(float f) {
  unsigned int u = __float_as_uint(f);
  u += 0x7FFFu + ((u >> 16) & 1u);  // RNE
  return (unsigned short)(u >> 16);
}
__device__ __forceinline__ float b2f(unsigned short s) {
  return __uint_as_float(((unsigned int)s) << 16);
}
__device__ __forceinline__ unsigned int pack2(float a, float b) {
  return (unsigned int)f2b(a) | ((unsigned int)f2b(b) << 16);
}
__device__ __forceinline__ f32x4 mfma32(bf16x8 a, bf16x8 b, f32x4 c) {
  return __builtin_amdgcn_mfma_f32_16x16x32_bf16(a, b, c, 0, 0, 0);
}
__device__ __forceinline__ f32x4 mfma16k(bf16x4 a, bf16x4 b, f32x4 c) {
  return __builtin_amdgcn_mfma_f32_16x16x16bf16_1k(a, b, c, 0, 0, 0);
}
__device__ __forceinline__ bf16x8 cvt8(const float* p) {
  float4 x = *(const float4*)p;
  float4 y = *(const float4*)(p + 4);
  union { unsigned int u[4]; bf16x8 v; } r;
  r.u[0] = pack2(x.x, x.y); r.u[1] = pack2(x.z, x.w);
  r.u[2] = pack2(y.x, y.y); r.u[3] = pack2(y.z, y.w);
  return r.v;
}

// -------- projections: per (n,h,z). Q/K swapped (D[d][s]) for row-major stores;
// V unswapped then stored transposed [d][s]. W converted fp32->bf16 in-LDS. --------
__global__ __launch_bounds__(256, 4) void proj_kernel(
    const float* __restrict__ qin, const float* __restrict__ kin, const float* __restrict__ vin,
    const float* __restrict__ Wq, const float* __restrict__ Wk, const float* __restrict__ Wv,
    unsigned short* __restrict__ Qp, unsigned short* __restrict__ Kp, unsigned short* __restrict__ Vp)
{
  __shared__ __align__(16) unsigned short Wl[64][72];
  const int tid = threadIdx.x, lane = tid & 63, w = tid >> 6;
  const int hi = lane >> 4, lo = lane & 15;
  const int z = blockIdx.z, nh = blockIdx.y, n = nh >> 3, h = nh & 7;
  const float* W = z == 0 ? Wq : (z == 1 ? Wk : Wv);
  const int srow = tid >> 2, scol = (tid & 3) * 16;
  *(bf16x8*)&Wl[srow][scol]     = cvt8(&W[srow * 64 + scol]);
  *(bf16x8*)&Wl[srow][scol + 8] = cvt8(&W[srow * 64 + scol + 8]);
  __syncthreads();

  const float* in = z == 0 ? qin : (z == 1 ? kin : vin);
  const int sx = blockIdx.x * 64 + w * 16 + lo;
  const float* src = in + ((size_t)(n * SEQ + sx)) * DM + h * HD + hi * 8;
  bf16x8 a0 = cvt8(src), a1 = cvt8(src + 32);

  f32x4 acc[4];
  #pragma unroll
  for (int t = 0; t < 4; ++t) acc[t] = (f32x4){0.f, 0.f, 0.f, 0.f};
  bf16x8 wf0[4], wf1[4];
  #pragma unroll
  for (int t = 0; t < 4; ++t) {
    wf0[t] = *(const bf16x8*)&Wl[t * 16 + lo][hi * 8];
    wf1[t] = *(const bf16x8*)&Wl[t * 16 + lo][32 + hi * 8];
  }
  if (z < 2) {
    #pragma unroll
    for (int t = 0; t < 4; ++t) {
      acc[t] = mfma32(wf0[t], a0, acc[t]);   // D[out_d][seq], seq=lo
      acc[t] = mfma32(wf1[t], a1, acc[t]);
    }
    unsigned short* outp = z == 0 ? Qp : Kp;
    unsigned short* dst = outp + ((size_t)(nh * SEQ + sx)) * HD + hi * 4;
    #pragma unroll
    for (int t = 0; t < 4; ++t) {
      uint2 u; u.x = pack2(acc[t][0], acc[t][1]); u.y = pack2(acc[t][2], acc[t][3]);
      *(uint2*)(dst + t * 16) = u;
    }
  } else {
    #pragma unroll
    for (int t = 0; t < 4; ++t) {
      acc[t] = mfma32(a0, wf0[t], acc[t]);   // D[seq][out_d], out_d=lo
      acc[t] = mfma32(a1, wf1[t], acc[t]);
    }
    const int rbase = blockIdx.x * 64 + w * 16 + hi * 4;
    #pragma unroll
    for (int t = 0; t < 4; ++t) {
      uint2 u; u.x = pack2(acc[t][0], acc[t][1]); u.y = pack2(acc[t][2], acc[t][3]);
      *(uint2*)&Vp[((size_t)(nh * HD + t * 16 + lo)) * SEQ + rbase] = u;
    }
  }
}

// -------- flash attention, swapped-QK in-register softmax --------
__global__ __launch_bounds__(256, 2) void attn_kernel(
    const unsigned short* __restrict__ Qp, const unsigned short* __restrict__ Kp,
    const unsigned short* __restrict__ Vp, const int* __restrict__ mask,
    unsigned short* __restrict__ AO)
{
  __shared__ __align__(16) unsigned short Kl[64][72];
  __shared__ __align__(16) unsigned short Vt[64][72];
  __shared__ float maskf[64];

  const int tid = threadIdx.x, lane = tid & 63, w = tid >> 6;
  const int hi = lane >> 4, lo = lane & 15;
  const int nh = blockIdx.y, n = nh >> 3, h = nh & 7;
  const int qb = blockIdx.x * 128 + w * 32;
  const float CS = 0.18033688011112042f;  // 0.125 * log2(e)

  bf16x8 qa[2][2];
  #pragma unroll
  for (int qs = 0; qs < 2; ++qs) {
    const unsigned short* qsrc = Qp + ((size_t)(nh * SEQ + qb + qs * 16 + lo)) * HD + hi * 8;
    qa[qs][0] = *(const bf16x8*)qsrc;
    qa[qs][1] = *(const bf16x8*)(qsrc + 32);
  }

  f32x4 o[2][4];
  #pragma unroll
  for (int qs = 0; qs < 2; ++qs)
    #pragma unroll
    for (int dt = 0; dt < 4; ++dt) o[qs][dt] = (f32x4){0.f, 0.f, 0.f, 0.f};
  float m[2] = {-1e30f, -1e30f}, l[2] = {0.f, 0.f};

  const int srow = tid >> 2, scol = (tid & 3) * 16;
  const unsigned short* Kb = Kp + ((size_t)(nh * SEQ + srow)) * HD + scol;
  const unsigned short* Vb = Vp + ((size_t)(nh * HD + srow)) * SEQ + scol;
  const int* Mb = mask + n * SEQ;

  for (int kv = 0; kv < SEQ / 64; ++kv) {
    const int kb = kv * 64;
    __syncthreads();
    *(int4*)&Kl[srow][scol]     = *(const int4*)(Kb + (size_t)kb * HD);
    *(int4*)&Kl[srow][scol + 8] = *(const int4*)(Kb + (size_t)kb * HD + 8);
    *(int4*)&Vt[srow][scol]     = *(const int4*)(Vb + kb);
    *(int4*)&Vt[srow][scol + 8] = *(const int4*)(Vb + kb + 8);
    if (tid < 64) maskf[tid] = Mb[kb + tid] ? 1.f : 0.f;
    __syncthreads();

    bf16x8 ka[4][2];
    #pragma unroll
    for (int t = 0; t < 4; ++t) {
      ka[t][0] = *(const bf16x8*)&Kl[t * 16 + lo][hi * 8];
      ka[t][1] = *(const bf16x8*)&Kl[t * 16 + lo][32 + hi * 8];
    }
    bf16x4 va[4][4];
    #pragma unroll
    for (int dt = 0; dt < 4; ++dt)
      #pragma unroll
      for (int t = 0; t < 4; ++t)
        va[dt][t] = *(const bf16x4*)&Vt[dt * 16 + lo][t * 16 + hi * 4];
    f32x4 mb[4];
    #pragma unroll
    for (int t = 0; t < 4; ++t) mb[t] = *(const f32x4*)&maskf[t * 16 + hi * 4];

    #pragma unroll
    for (int qs = 0; qs < 2; ++qs) {
      // St = K . Q^T : lane holds St[key = t*16+hi*4+j][q = lo]
      f32x4 st[4];
      #pragma unroll
      for (int t = 0; t < 4; ++t) {
        st[t] = mfma32(ka[t][0], qa[qs][0], (f32x4){0.f, 0.f, 0.f, 0.f});
        st[t] = mfma32(ka[t][1], qa[qs][1], st[t]);
      }
      // row max over all 64 keys for q = lo (max over raw scores; softmax is
      // shift-invariant and masked keys get exact-zero p via multiply)
      f32x4 mx;
      #pragma unroll
      for (int j = 0; j < 4; ++j)
        mx[j] = fmaxf(fmaxf(st[0][j], st[1][j]), fmaxf(st[2][j], st[3][j]));
      float mxx = fmaxf(fmaxf(mx[0], mx[1]), fmaxf(mx[2], mx[3]));
      mxx = fmaxf(mxx, __shfl_xor(mxx, 16));
      mxx = fmaxf(mxx, __shfl_xor(mxx, 32));
      const float nm = fmaxf(m[qs], mxx);
      const float sc = exp2f((m[qs] - nm) * CS);
      m[qs] = nm;
      const float mc = -nm * CS;

      bf16x4 pf[4];
      float prs = 0.f;
      #pragma unroll
      for (int t = 0; t < 4; ++t) {
        union { unsigned short s[4]; bf16x4 v; } pu;
        #pragma unroll
        for (int j = 0; j < 4; ++j) {
          float p = exp2f(fmaf(st[t][j], CS, mc)) * mb[t][j];
          unsigned short us = f2b(p);
          pu.s[j] = us;
          prs += b2f(us);  // sum the rounded values: consistent with PV numerator
        }
        pf[t] = pu.v;
      }
      prs += __shfl_xor(prs, 16);
      prs += __shfl_xor(prs, 32);
      l[qs] = l[qs] * sc + prs;
      #pragma unroll
      for (int dt = 0; dt < 4; ++dt) o[qs][dt] *= sc;
      // O^T[d][q] += V^T . P^T  (St C-layout == 16x16x16 B-frag layout)
      #pragma unroll
      for (int dt = 0; dt < 4; ++dt)
        #pragma unroll
        for (int t = 0; t < 4; ++t)
          o[qs][dt] = mfma16k(va[dt][t], pf[t], o[qs][dt]);
    }
  }

  #pragma unroll
  for (int qs = 0; qs < 2; ++qs) {
    const float rl = 1.f / l[qs];
    unsigned short* dst = AO + ((size_t)(n * SEQ + qb + qs * 16 + lo)) * DM + h * HD + hi * 4;
    #pragma unroll
    for (int dt = 0; dt < 4; ++dt) {
      f32x4 v = o[qs][dt] * rl;
      uint2 u; u.x = pack2(v[0], v[1]); u.y = pack2(v[2], v[3]);
      *(uint2*)(dst + dt * 16) = u;
    }
  }
}

// -------- FC: out = AO @ Wfc^T + bfc (swapped -> float4 stores) --------
__global__ __launch_bounds__(256, 4) void fc_kernel(
    const unsigned short* __restrict__ AO, const float* __restrict__ Wfc,
    const float* __restrict__ bfc, float* __restrict__ out)
{
  __shared__ __align__(16) unsigned short Al[64][72];
  __shared__ __align__(16) unsigned short Bl[64][72];
  const int tid = threadIdx.x, lane = tid & 63, w = tid >> 6;
  const int hi = lane >> 4, lo = lane & 15;
  const int rb = blockIdx.x * 64, cb = blockIdx.y * 64;
  const int srow = tid >> 2, scol = (tid & 3) * 16;
  const unsigned short* Ab = AO + (size_t)(rb + srow) * DM + scol;
  const float* Bb = Wfc + (size_t)(cb + srow) * DM + scol;

  f32x4 acc[4];
  #pragma unroll
  for (int t = 0; t < 4; ++t) acc[t] = (f32x4){0.f, 0.f, 0.f, 0.f};

  for (int i = 0; i < 8; ++i) {
    const int kn = i * 64;
    __syncthreads();
    *(int4*)&Al[srow][scol]      = *(const int4*)(Ab + kn);
    *(int4*)&Al[srow][scol + 8]  = *(const int4*)(Ab + kn + 8);
    *(bf16x8*)&Bl[srow][scol]     = cvt8(Bb + kn);
    *(bf16x8*)&Bl[srow][scol + 8] = cvt8(Bb + kn + 8);
    __syncthreads();

    bf16x8 a0 = *(const bf16x8*)&Al[w * 16 + lo][hi * 8];
    bf16x8 a1 = *(const bf16x8*)&Al[w * 16 + lo][32 + hi * 8];
    #pragma unroll
    for (int t = 0; t < 4; ++t) {
      bf16x8 w0 = *(const bf16x8*)&Bl[t * 16 + lo][hi * 8];
      bf16x8 w1 = *(const bf16x8*)&Bl[t * 16 + lo][32 + hi * 8];
      acc[t] = mfma32(w0, a0, acc[t]);   // D[out_d][seq], seq=lo
      acc[t] = mfma32(w1, a1, acc[t]);
    }
  }

  const int orow = rb + w * 16 + lo;
  float* dst = out + (size_t)orow * DM + cb + hi * 4;
  #pragma unroll
  for (int t = 0; t < 4; ++t) {
    float4 b4 = *(const float4*)&bfc[cb + t * 16 + hi * 4];
    float4 v;
    v.x = acc[t][0] + b4.x; v.y = acc[t][1] + b4.y;
    v.z = acc[t][2] + b4.z; v.w = acc[t][3] + b4.w;
    *(float4*)(dst + t * 16) = v;
  }
}

extern "C" void kernel_launch(void* const* d_in, const int* in_sizes, int n_in,
                              void* d_out, int out_size, void* d_ws, size_t ws_size,
                              hipStream_t stream) {
  const float* value = (const float*)d_in[0];
  const float* key   = (const float*)d_in[1];
  const float* query = (const float*)d_in[2];
  const int*   mask  = (const int*)d_in[3];
  const float* Wv    = (const float*)d_in[4];
  const float* Wk    = (const float*)d_in[5];
  const float* Wq    = (const float*)d_in[6];
  const float* Wfc   = (const float*)d_in[7];
  const float* bfc   = (const float*)d_in[8];
  float* out = (float*)d_out;

  const size_t per = (size_t)N_B * NH * SEQ * HD;  // 4,194,304 elems; 4 bufs = 32 MiB exactly
  unsigned short* Qp = (unsigned short*)d_ws;
  unsigned short* Kp = Qp + per;
  unsigned short* Vp = Kp + per;
  unsigned short* AO = Vp + per;

  proj_kernel<<<dim3(SEQ / 64, N_B * NH, 3), 256, 0, stream>>>(
      query, key, value, Wq, Wk, Wv, Qp, Kp, Vp);
  attn_kernel<<<dim3(SEQ / 128, N_B * NH), 256, 0, stream>>>(Qp, Kp, Vp, mask, AO);
  fc_kernel<<<dim3(N_B * SEQ / 64, DM / 64), 256, 0, stream>>>(AO, Wfc, bfc, out);
}

// Round 5
// 196.970 us; speedup vs baseline: 1.2545x; 1.1313x over previous
//
#include <hip/hip_runtime.h>
#include <hip/hip_bf16.h>

#define N_B 4
#define SEQ 2048
#define NH 8
#define HD 64
#define DM 512

typedef __attribute__((ext_vector_type(8))) short bf16x8;
typedef __attribute__((ext_vector_type(4))) short bf16x4;
typedef __attribute__((ext_vector_type(4))) float f32x4;

#if __has_builtin(__builtin_amdgcn_exp2f)
#define EXP2(x) __builtin_amdgcn_exp2f(x)
#else
#define EXP2(x) exp2f(x)
#endif

__device__ __forceinline__ unsigned short b16(float f) {
  return __bfloat16_as_ushort(__float2bfloat16(f));
}
__device__ __forceinline__ f32x4 mfma32(bf16x8 a, bf16x8 b, f32x4 c) {
  return __builtin_amdgcn_mfma_f32_16x16x32_bf16(a, b, c, 0, 0, 0);
}
__device__ __forceinline__ f32x4 mfma16k(bf16x4 a, bf16x4 b, f32x4 c) {
  return __builtin_amdgcn_mfma_f32_16x16x16bf16_1k(a, b, c, 0, 0, 0);
}
__device__ __forceinline__ bf16x8 cvt8(const float* p) {
  float4 x = *(const float4*)p;
  float4 y = *(const float4*)(p + 4);
  union { unsigned short s[8]; bf16x8 v; } r;
  r.s[0] = b16(x.x); r.s[1] = b16(x.y); r.s[2] = b16(x.z); r.s[3] = b16(x.w);
  r.s[4] = b16(y.x); r.s[5] = b16(y.y); r.s[6] = b16(y.z); r.s[7] = b16(y.w);
  return r.v;
}
__device__ __forceinline__ bf16x8 cvt8v(float4 x, float4 y) {
  union { unsigned short s[8]; bf16x8 v; } r;
  r.s[0] = b16(x.x); r.s[1] = b16(x.y); r.s[2] = b16(x.z); r.s[3] = b16(x.w);
  r.s[4] = b16(y.x); r.s[5] = b16(y.y); r.s[6] = b16(y.z); r.s[7] = b16(y.w);
  return r.v;
}

// -------- projections: out = X @ W^T per (n,h,z), all unswapped D[s][d].
// Q/K stored [s][d] (u16 coalesced stores); V stored transposed [d][s'] with
// column permutation within each 64-block: pos(k = t*16+h4*4+e) = h4*16+t*4+e,
// so attention fetches each lane's 4 PV B-fragments with two ds_read_b128. --------
__global__ __launch_bounds__(256, 4) void proj_kernel(
    const float* __restrict__ qin, const float* __restrict__ kin, const float* __restrict__ vin,
    const float* __restrict__ Wq, const float* __restrict__ Wk, const float* __restrict__ Wv,
    unsigned short* __restrict__ Qp, unsigned short* __restrict__ Kp, unsigned short* __restrict__ Vp)
{
  __shared__ __align__(16) unsigned short Wl[64][72];
  const int tid = threadIdx.x, lane = tid & 63, w = tid >> 6;
  const int hi = lane >> 4, lo = lane & 15;
  const int z = blockIdx.z, nh = blockIdx.y, n = nh >> 3, h = nh & 7;
  const float* W = z == 0 ? Wq : (z == 1 ? Wk : Wv);
  const int srow = tid >> 2, scol = (tid & 3) * 16;
  *(bf16x8*)&Wl[srow][scol]     = cvt8(&W[srow * 64 + scol]);
  *(bf16x8*)&Wl[srow][scol + 8] = cvt8(&W[srow * 64 + scol + 8]);
  __syncthreads();

  const float* in = z == 0 ? qin : (z == 1 ? kin : vin);
  const int sx = blockIdx.x * 64 + w * 16 + lo;
  const float* src = in + ((size_t)(n * SEQ + sx)) * DM + h * HD + hi * 8;
  bf16x8 a0 = cvt8(src), a1 = cvt8(src + 32);

  f32x4 acc[4];
  #pragma unroll
  for (int t = 0; t < 4; ++t) acc[t] = (f32x4){0.f, 0.f, 0.f, 0.f};
  #pragma unroll
  for (int t = 0; t < 4; ++t) {
    bf16x8 wf0 = *(const bf16x8*)&Wl[t * 16 + lo][hi * 8];
    bf16x8 wf1 = *(const bf16x8*)&Wl[t * 16 + lo][32 + hi * 8];
    acc[t] = mfma32(a0, wf0, acc[t]);   // D[s][d]: row = seq (hi*4+j), col = out_d (lo)
    acc[t] = mfma32(a1, wf1, acc[t]);
  }

  if (z < 2) {
    unsigned short* outp = z == 0 ? Qp : Kp;
    const size_t rowb = (size_t)(nh * SEQ + blockIdx.x * 64 + w * 16 + hi * 4);
    #pragma unroll
    for (int t = 0; t < 4; ++t)
      #pragma unroll
      for (int j = 0; j < 4; ++j)
        outp[(rowb + j) * HD + t * 16 + lo] = b16(acc[t][j]);
  } else {
    // V^T[d][s'], s' = block*64 + hi*16 + w*4 + j  (permuted within 64-block)
    const int cb = blockIdx.x * 64 + hi * 16 + w * 4;
    #pragma unroll
    for (int t = 0; t < 4; ++t) {
      union { unsigned short s[4]; uint2 u; } p;
      p.s[0] = b16(acc[t][0]); p.s[1] = b16(acc[t][1]);
      p.s[2] = b16(acc[t][2]); p.s[3] = b16(acc[t][3]);
      *(uint2*)&Vp[((size_t)(nh * HD + t * 16 + lo)) * SEQ + cb] = p.u;
    }
  }
}

// -------- flash attention: swapped QK^T, in-register softmax, defer-max,
// register-prefetch staging, b128 V fragments --------
__global__ __launch_bounds__(256, 2) void attn_kernel(
    const unsigned short* __restrict__ Qp, const unsigned short* __restrict__ Kp,
    const unsigned short* __restrict__ Vp, const int* __restrict__ mask,
    unsigned short* __restrict__ AO)
{
  __shared__ __align__(16) unsigned short Kl[64][72];
  __shared__ __align__(16) unsigned short Vt[64][72];
  __shared__ float maskf[64];

  const int tid = threadIdx.x, lane = tid & 63, w = tid >> 6;
  const int hi = lane >> 4, lo = lane & 15;
  const int nh = blockIdx.y, n = nh >> 3, h = nh & 7;
  const int qb = blockIdx.x * 128 + w * 32;
  const float CS = 0.18033688011112042f;  // 0.125 * log2(e)
  const float THR = 44.0f;                // defer-max threshold: P bounded by ~2^8

  bf16x8 qa[2][2];
  #pragma unroll
  for (int qs = 0; qs < 2; ++qs) {
    const unsigned short* qsrc = Qp + ((size_t)(nh * SEQ + qb + qs * 16 + lo)) * HD + hi * 8;
    qa[qs][0] = *(const bf16x8*)qsrc;
    qa[qs][1] = *(const bf16x8*)(qsrc + 32);
  }

  f32x4 o[2][4];
  #pragma unroll
  for (int qs = 0; qs < 2; ++qs)
    #pragma unroll
    for (int dt = 0; dt < 4; ++dt) o[qs][dt] = (f32x4){0.f, 0.f, 0.f, 0.f};
  float m[2] = {-1e30f, -1e30f}, l[2] = {0.f, 0.f};

  const int srow = tid >> 2, scol = (tid & 3) * 16;
  const unsigned short* Kb = Kp + ((size_t)(nh * SEQ + srow)) * HD + scol;
  const unsigned short* Vb = Vp + ((size_t)(nh * HD + srow)) * SEQ + scol;
  const int* Mb = mask + n * SEQ;

  // prefetch tile 0 into registers
  int4 kr0 = *(const int4*)Kb, kr1 = *(const int4*)(Kb + 8);
  int4 vr0 = *(const int4*)Vb, vr1 = *(const int4*)(Vb + 8);
  int mp = (tid < 64) ? Mb[tid] : 0;

  for (int kv = 0; kv < SEQ / 64; ++kv) {
    __syncthreads();   // all waves done reading LDS from previous tile
    *(int4*)&Kl[srow][scol] = kr0; *(int4*)&Kl[srow][scol + 8] = kr1;
    *(int4*)&Vt[srow][scol] = vr0; *(int4*)&Vt[srow][scol + 8] = vr1;
    if (tid < 64) maskf[tid] = mp ? 1.f : 0.f;
    {  // issue next-tile loads now; consumed next iteration (latency hidden)
      const int kb2 = ((kv + 1) & 31) * 64;
      kr0 = *(const int4*)(Kb + (size_t)kb2 * HD);
      kr1 = *(const int4*)(Kb + (size_t)kb2 * HD + 8);
      vr0 = *(const int4*)(Vb + kb2);
      vr1 = *(const int4*)(Vb + kb2 + 8);
      if (tid < 64) mp = Mb[kb2 + tid];
    }
    __syncthreads();   // current tile visible to all waves

    bf16x8 ka[4][2];
    #pragma unroll
    for (int t = 0; t < 4; ++t) {
      ka[t][0] = *(const bf16x8*)&Kl[t * 16 + lo][hi * 8];
      ka[t][1] = *(const bf16x8*)&Kl[t * 16 + lo][32 + hi * 8];
    }
    // V fragments: permuted layout puts this lane's 4 k-slot frags at
    // cols hi*16 .. hi*16+15 -> two b128 reads per dt
    union V16 { bf16x8 v8[2]; bf16x4 v4[4]; };
    V16 vv[4];
    #pragma unroll
    for (int dt = 0; dt < 4; ++dt) {
      vv[dt].v8[0] = *(const bf16x8*)&Vt[dt * 16 + lo][hi * 16];
      vv[dt].v8[1] = *(const bf16x8*)&Vt[dt * 16 + lo][hi * 16 + 8];
    }
    f32x4 mb[4];
    #pragma unroll
    for (int t = 0; t < 4; ++t) mb[t] = *(const f32x4*)&maskf[t * 16 + hi * 4];

    #pragma unroll
    for (int qs = 0; qs < 2; ++qs) {
      // St = K . Q^T : lane holds St[key = t*16+hi*4+j][q = lo]
      f32x4 st[4];
      #pragma unroll
      for (int t = 0; t < 4; ++t) {
        st[t] = mfma32(ka[t][0], qa[qs][0], (f32x4){0.f, 0.f, 0.f, 0.f});
        st[t] = mfma32(ka[t][1], qa[qs][1], st[t]);
      }
      f32x4 mx;
      #pragma unroll
      for (int j = 0; j < 4; ++j)
        mx[j] = fmaxf(fmaxf(st[0][j], st[1][j]), fmaxf(st[2][j], st[3][j]));
      float mxx = fmaxf(fmaxf(mx[0], mx[1]), fmaxf(mx[2], mx[3]));
      mxx = fmaxf(mxx, __shfl_xor(mxx, 16));
      mxx = fmaxf(mxx, __shfl_xor(mxx, 32));
      if (!__all(mxx - m[qs] <= THR)) {   // rescale only on significant max growth
        const float nm = fmaxf(m[qs], mxx);
        const float sc = EXP2((m[qs] - nm) * CS);
        m[qs] = nm;
        l[qs] *= sc;
        #pragma unroll
        for (int dt = 0; dt < 4; ++dt) o[qs][dt] *= sc;
      }
      const float mc = -m[qs] * CS;

      f32x4 pv[4];
      #pragma unroll
      for (int t = 0; t < 4; ++t)
        #pragma unroll
        for (int j = 0; j < 4; ++j)
          pv[t][j] = EXP2(fmaf(st[t][j], CS, mc)) * mb[t][j];
      f32x4 ps = pv[0] + pv[1] + pv[2] + pv[3];
      float prs = ps[0] + ps[1] + ps[2] + ps[3];
      prs += __shfl_xor(prs, 16);
      prs += __shfl_xor(prs, 32);
      l[qs] += prs;

      bf16x4 pf[4];
      #pragma unroll
      for (int t = 0; t < 4; ++t) {
        union { unsigned short s[4]; bf16x4 v; } pu;
        pu.s[0] = b16(pv[t][0]); pu.s[1] = b16(pv[t][1]);
        pu.s[2] = b16(pv[t][2]); pu.s[3] = b16(pv[t][3]);
        pf[t] = pu.v;
      }
      // O^T[d][q] += V^T . P^T
      #pragma unroll
      for (int dt = 0; dt < 4; ++dt)
        #pragma unroll
        for (int t = 0; t < 4; ++t)
          o[qs][dt] = mfma16k(vv[dt].v4[t], pf[t], o[qs][dt]);
    }
  }

  #pragma unroll
  for (int qs = 0; qs < 2; ++qs) {
    const float rl = 1.f / l[qs];
    unsigned short* dst = AO + ((size_t)(n * SEQ + qb + qs * 16 + lo)) * DM + h * HD + hi * 4;
    #pragma unroll
    for (int dt = 0; dt < 4; ++dt) {
      f32x4 v = o[qs][dt] * rl;
      union { unsigned short s[4]; uint2 u; } p;
      p.s[0] = b16(v[0]); p.s[1] = b16(v[1]); p.s[2] = b16(v[2]); p.s[3] = b16(v[3]);
      *(uint2*)(dst + dt * 16) = p.u;
    }
  }
}

// -------- FC: out = AO @ Wfc^T + bfc, unswapped (coalesced f32 stores) --------
__global__ __launch_bounds__(256, 4) void fc_kernel(
    const unsigned short* __restrict__ AO, const float* __restrict__ Wfc,
    const float* __restrict__ bfc, float* __restrict__ out)
{
  __shared__ __align__(16) unsigned short Al[64][72];
  __shared__ __align__(16) unsigned short Bl[64][72];
  const int tid = threadIdx.x, lane = tid & 63, w = tid >> 6;
  const int hi = lane >> 4, lo = lane & 15;
  const int rb = blockIdx.x * 64, cb = blockIdx.y * 64;
  const int srow = tid >> 2, scol = (tid & 3) * 16;
  const unsigned short* Ab = AO + (size_t)(rb + srow) * DM + scol;
  const float* Bb = Wfc + (size_t)(cb + srow) * DM + scol;

  // prefetch k-block 0
  int4 ar0 = *(const int4*)Ab, ar1 = *(const int4*)(Ab + 8);
  float4 wr0 = *(const float4*)Bb,        wr1 = *(const float4*)(Bb + 4);
  float4 wr2 = *(const float4*)(Bb + 8),  wr3 = *(const float4*)(Bb + 12);

  f32x4 acc[4];
  #pragma unroll
  for (int t = 0; t < 4; ++t) acc[t] = (f32x4){0.f, 0.f, 0.f, 0.f};

  for (int i = 0; i < 8; ++i) {
    __syncthreads();
    *(int4*)&Al[srow][scol] = ar0; *(int4*)&Al[srow][scol + 8] = ar1;
    *(bf16x8*)&Bl[srow][scol]     = cvt8v(wr0, wr1);
    *(bf16x8*)&Bl[srow][scol + 8] = cvt8v(wr2, wr3);
    {
      const int kn = ((i + 1) & 7) * 64;
      ar0 = *(const int4*)(Ab + kn); ar1 = *(const int4*)(Ab + kn + 8);
      wr0 = *(const float4*)(Bb + kn);      wr1 = *(const float4*)(Bb + kn + 4);
      wr2 = *(const float4*)(Bb + kn + 8);  wr3 = *(const float4*)(Bb + kn + 12);
    }
    __syncthreads();

    bf16x8 a0 = *(const bf16x8*)&Al[w * 16 + lo][hi * 8];
    bf16x8 a1 = *(const bf16x8*)&Al[w * 16 + lo][32 + hi * 8];
    #pragma unroll
    for (int t = 0; t < 4; ++t) {
      bf16x8 w0 = *(const bf16x8*)&Bl[t * 16 + lo][hi * 8];
      bf16x8 w1 = *(const bf16x8*)&Bl[t * 16 + lo][32 + hi * 8];
      acc[t] = mfma32(a0, w0, acc[t]);   // D[s][out_d]: row = seq, col = out_d (lo)
      acc[t] = mfma32(a1, w1, acc[t]);
    }
  }

  const int rowb = rb + w * 16 + hi * 4;
  #pragma unroll
  for (int t = 0; t < 4; ++t) {
    const float bias = bfc[cb + t * 16 + lo];
    #pragma unroll
    for (int j = 0; j < 4; ++j)
      out[(size_t)(rowb + j) * DM + cb + t * 16 + lo] = acc[t][j] + bias;
  }
}

extern "C" void kernel_launch(void* const* d_in, const int* in_sizes, int n_in,
                              void* d_out, int out_size, void* d_ws, size_t ws_size,
                              hipStream_t stream) {
  const float* value = (const float*)d_in[0];
  const float* key   = (const float*)d_in[1];
  const float* query = (const float*)d_in[2];
  const int*   mask  = (const int*)d_in[3];
  const float* Wv    = (const float*)d_in[4];
  const float* Wk    = (const float*)d_in[5];
  const float* Wq    = (const float*)d_in[6];
  const float* Wfc   = (const float*)d_in[7];
  const float* bfc   = (const float*)d_in[8];
  float* out = (float*)d_out;

  const size_t per = (size_t)N_B * NH * SEQ * HD;  // 4,194,304 elems; 4 bufs = 32 MiB exactly
  unsigned short* Qp = (unsigned short*)d_ws;
  unsigned short* Kp = Qp + per;
  unsigned short* Vp = Kp + per;
  unsigned short* AO = Vp + per;

  proj_kernel<<<dim3(SEQ / 64, N_B * NH, 3), 256, 0, stream>>>(
      query, key, value, Wq, Wk, Wv, Qp, Kp, Vp);
  attn_kernel<<<dim3(SEQ / 128, N_B * NH), 256, 0, stream>>>(Qp, Kp, Vp, mask, AO);
  fc_kernel<<<dim3(N_B * SEQ / 64, DM / 64), 256, 0, stream>>>(AO, Wfc, bfc, out);
}

// Round 6
// 191.762 us; speedup vs baseline: 1.2886x; 1.0272x over previous
//
#include <hip/hip_runtime.h>
#include <hip/hip_bf16.h>

#define N_B 4
#define SEQ 2048
#define NH 8
#define HD 64
#define DM 512

typedef __attribute__((ext_vector_type(8))) short bf16x8;
typedef __attribute__((ext_vector_type(4))) short bf16x4;
typedef __attribute__((ext_vector_type(4))) float f32x4;

#if __has_builtin(__builtin_amdgcn_exp2f)
#define EXP2(x) __builtin_amdgcn_exp2f(x)
#else
#define EXP2(x) exp2f(x)
#endif

__device__ __forceinline__ unsigned short b16(float f) {
  return __bfloat16_as_ushort(__float2bfloat16(f));
}
__device__ __forceinline__ f32x4 mfma32(bf16x8 a, bf16x8 b, f32x4 c) {
  return __builtin_amdgcn_mfma_f32_16x16x32_bf16(a, b, c, 0, 0, 0);
}
__device__ __forceinline__ f32x4 mfma16k(bf16x4 a, bf16x4 b, f32x4 c) {
  return __builtin_amdgcn_mfma_f32_16x16x16bf16_1k(a, b, c, 0, 0, 0);
}
__device__ __forceinline__ bf16x8 cvt8(const float* p) {
  float4 x = *(const float4*)p;
  float4 y = *(const float4*)(p + 4);
  union { unsigned short s[8]; bf16x8 v; } r;
  r.s[0] = b16(x.x); r.s[1] = b16(x.y); r.s[2] = b16(x.z); r.s[3] = b16(x.w);
  r.s[4] = b16(y.x); r.s[5] = b16(y.y); r.s[6] = b16(y.z); r.s[7] = b16(y.w);
  return r.v;
}
__device__ __forceinline__ bf16x8 cvt8v(float4 x, float4 y) {
  union { unsigned short s[8]; bf16x8 v; } r;
  r.s[0] = b16(x.x); r.s[1] = b16(x.y); r.s[2] = b16(x.z); r.s[3] = b16(x.w);
  r.s[4] = b16(y.x); r.s[5] = b16(y.y); r.s[6] = b16(y.z); r.s[7] = b16(y.w);
  return r.v;
}

// -------- projections: out = X @ W^T per (n,h,z).
// Q/K computed SWAPPED (D[out_d][s]) -> uint2 stores into [s][d] layout
// (verified round 3). V unswapped, stored transposed-permuted [d][s']
// with s'(w*16+hi*4+j) = hi*16+w*4+j within each 64-block (verified round 5). --------
__global__ __launch_bounds__(256, 4) void proj_kernel(
    const float* __restrict__ qin, const float* __restrict__ kin, const float* __restrict__ vin,
    const float* __restrict__ Wq, const float* __restrict__ Wk, const float* __restrict__ Wv,
    unsigned short* __restrict__ Qp, unsigned short* __restrict__ Kp, unsigned short* __restrict__ Vp)
{
  __shared__ __align__(16) unsigned short Wl[64][72];
  const int tid = threadIdx.x, lane = tid & 63, w = tid >> 6;
  const int hi = lane >> 4, lo = lane & 15;
  const int z = blockIdx.z, nh = blockIdx.y, n = nh >> 3, h = nh & 7;
  const float* W = z == 0 ? Wq : (z == 1 ? Wk : Wv);
  const int srow = tid >> 2, scol = (tid & 3) * 16;
  *(bf16x8*)&Wl[srow][scol]     = cvt8(&W[srow * 64 + scol]);
  *(bf16x8*)&Wl[srow][scol + 8] = cvt8(&W[srow * 64 + scol + 8]);
  __syncthreads();

  const float* in = z == 0 ? qin : (z == 1 ? kin : vin);
  const int sx = blockIdx.x * 64 + w * 16 + lo;
  const float* src = in + ((size_t)(n * SEQ + sx)) * DM + h * HD + hi * 8;
  bf16x8 a0 = cvt8(src), a1 = cvt8(src + 32);

  f32x4 acc[4];
  #pragma unroll
  for (int t = 0; t < 4; ++t) acc[t] = (f32x4){0.f, 0.f, 0.f, 0.f};
  bf16x8 wf0[4], wf1[4];
  #pragma unroll
  for (int t = 0; t < 4; ++t) {
    wf0[t] = *(const bf16x8*)&Wl[t * 16 + lo][hi * 8];
    wf1[t] = *(const bf16x8*)&Wl[t * 16 + lo][32 + hi * 8];
  }

  if (z < 2) {
    // swapped: D[out_d][s], s = lo -> 4x uint2 stores along d
    #pragma unroll
    for (int t = 0; t < 4; ++t) {
      acc[t] = mfma32(wf0[t], a0, acc[t]);
      acc[t] = mfma32(wf1[t], a1, acc[t]);
    }
    unsigned short* outp = z == 0 ? Qp : Kp;
    unsigned short* dst = outp + ((size_t)(nh * SEQ + sx)) * HD + hi * 4;
    #pragma unroll
    for (int t = 0; t < 4; ++t) {
      union { unsigned short s[4]; uint2 u; } p;
      p.s[0] = b16(acc[t][0]); p.s[1] = b16(acc[t][1]);
      p.s[2] = b16(acc[t][2]); p.s[3] = b16(acc[t][3]);
      *(uint2*)(dst + t * 16) = p.u;
    }
  } else {
    // unswapped: D[s][d]; store V^T[d][s'] permuted within 64-block
    #pragma unroll
    for (int t = 0; t < 4; ++t) {
      acc[t] = mfma32(a0, wf0[t], acc[t]);
      acc[t] = mfma32(a1, wf1[t], acc[t]);
    }
    const int cb = blockIdx.x * 64 + hi * 16 + w * 4;
    #pragma unroll
    for (int t = 0; t < 4; ++t) {
      union { unsigned short s[4]; uint2 u; } p;
      p.s[0] = b16(acc[t][0]); p.s[1] = b16(acc[t][1]);
      p.s[2] = b16(acc[t][2]); p.s[3] = b16(acc[t][3]);
      *(uint2*)&Vp[((size_t)(nh * HD + t * 16 + lo)) * SEQ + cb] = p.u;
    }
  }
}

// -------- flash attention: swapped QK^T in-register softmax, defer-max,
// LDS DOUBLE-BUFFER (1 barrier/tile, load latency hidden under compute) --------
__global__ __launch_bounds__(256, 2) void attn_kernel(
    const unsigned short* __restrict__ Qp, const unsigned short* __restrict__ Kp,
    const unsigned short* __restrict__ Vp, const int* __restrict__ mask,
    unsigned short* __restrict__ AO)
{
  __shared__ __align__(16) unsigned short Kl[2][64][72];
  __shared__ __align__(16) unsigned short Vt[2][64][72];
  __shared__ float maskf[2][64];

  const int tid = threadIdx.x, lane = tid & 63, w = tid >> 6;
  const int hi = lane >> 4, lo = lane & 15;
  const int nh = blockIdx.y, n = nh >> 3, h = nh & 7;
  const int qb = blockIdx.x * 128 + w * 32;
  const float CS = 0.18033688011112042f;  // 0.125 * log2(e)
  const float THR = 44.0f;                // defer-max: P bounded by ~2^8

  bf16x8 qa[2][2];
  #pragma unroll
  for (int qs = 0; qs < 2; ++qs) {
    const unsigned short* qsrc = Qp + ((size_t)(nh * SEQ + qb + qs * 16 + lo)) * HD + hi * 8;
    qa[qs][0] = *(const bf16x8*)qsrc;
    qa[qs][1] = *(const bf16x8*)(qsrc + 32);
  }

  f32x4 o[2][4];
  #pragma unroll
  for (int qs = 0; qs < 2; ++qs)
    #pragma unroll
    for (int dt = 0; dt < 4; ++dt) o[qs][dt] = (f32x4){0.f, 0.f, 0.f, 0.f};
  float m[2] = {-1e30f, -1e30f}, l[2] = {0.f, 0.f};

  const int srow = tid >> 2, scol = (tid & 3) * 16;
  const unsigned short* Kb = Kp + ((size_t)(nh * SEQ + srow)) * HD + scol;
  const unsigned short* Vb = Vp + ((size_t)(nh * HD + srow)) * SEQ + scol;
  const int* Mb = mask + n * SEQ;

  // prologue: tile 0 -> buf 0
  {
    int4 k0 = *(const int4*)Kb, k1 = *(const int4*)(Kb + 8);
    int4 v0 = *(const int4*)Vb, v1 = *(const int4*)(Vb + 8);
    *(int4*)&Kl[0][srow][scol] = k0; *(int4*)&Kl[0][srow][scol + 8] = k1;
    *(int4*)&Vt[0][srow][scol] = v0; *(int4*)&Vt[0][srow][scol + 8] = v1;
    if (tid < 64) maskf[0][tid] = Mb[tid] ? 1.f : 0.f;
  }
  __syncthreads();

  for (int kv = 0; kv < SEQ / 64; ++kv) {
    const int cur = kv & 1;
    // issue loads for tile kv+1 (wraps harmlessly at the end)
    const int kb2 = ((kv + 1) & 31) * 64;
    int4 kr0 = *(const int4*)(Kb + (size_t)kb2 * HD);
    int4 kr1 = *(const int4*)(Kb + (size_t)kb2 * HD + 8);
    int4 vr0 = *(const int4*)(Vb + kb2);
    int4 vr1 = *(const int4*)(Vb + kb2 + 8);
    int mp = (tid < 64) ? Mb[kb2 + tid] : 0;

    // ---- compute on buf[cur] ----
    bf16x8 ka[4][2];
    #pragma unroll
    for (int t = 0; t < 4; ++t) {
      ka[t][0] = *(const bf16x8*)&Kl[cur][t * 16 + lo][hi * 8];
      ka[t][1] = *(const bf16x8*)&Kl[cur][t * 16 + lo][32 + hi * 8];
    }
    union V16 { bf16x8 v8[2]; bf16x4 v4[4]; };
    V16 vv[4];
    #pragma unroll
    for (int dt = 0; dt < 4; ++dt) {
      vv[dt].v8[0] = *(const bf16x8*)&Vt[cur][dt * 16 + lo][hi * 16];
      vv[dt].v8[1] = *(const bf16x8*)&Vt[cur][dt * 16 + lo][hi * 16 + 8];
    }
    f32x4 mb[4];
    #pragma unroll
    for (int t = 0; t < 4; ++t) mb[t] = *(const f32x4*)&maskf[cur][t * 16 + hi * 4];

    #pragma unroll
    for (int qs = 0; qs < 2; ++qs) {
      f32x4 st[4];
      #pragma unroll
      for (int t = 0; t < 4; ++t) {
        st[t] = mfma32(ka[t][0], qa[qs][0], (f32x4){0.f, 0.f, 0.f, 0.f});
        st[t] = mfma32(ka[t][1], qa[qs][1], st[t]);
      }
      f32x4 mx;
      #pragma unroll
      for (int j = 0; j < 4; ++j)
        mx[j] = fmaxf(fmaxf(st[0][j], st[1][j]), fmaxf(st[2][j], st[3][j]));
      float mxx = fmaxf(fmaxf(mx[0], mx[1]), fmaxf(mx[2], mx[3]));
      mxx = fmaxf(mxx, __shfl_xor(mxx, 16));
      mxx = fmaxf(mxx, __shfl_xor(mxx, 32));
      if (!__all(mxx - m[qs] <= THR)) {
        const float nm = fmaxf(m[qs], mxx);
        const float sc = EXP2((m[qs] - nm) * CS);
        m[qs] = nm;
        l[qs] *= sc;
        #pragma unroll
        for (int dt = 0; dt < 4; ++dt) o[qs][dt] *= sc;
      }
      const float mc = -m[qs] * CS;

      f32x4 pv[4];
      #pragma unroll
      for (int t = 0; t < 4; ++t)
        #pragma unroll
        for (int j = 0; j < 4; ++j)
          pv[t][j] = EXP2(fmaf(st[t][j], CS, mc)) * mb[t][j];
      f32x4 ps = pv[0] + pv[1] + pv[2] + pv[3];
      float prs = ps[0] + ps[1] + ps[2] + ps[3];
      prs += __shfl_xor(prs, 16);
      prs += __shfl_xor(prs, 32);
      l[qs] += prs;

      bf16x4 pf[4];
      #pragma unroll
      for (int t = 0; t < 4; ++t) {
        union { unsigned short s[4]; bf16x4 v; } pu;
        pu.s[0] = b16(pv[t][0]); pu.s[1] = b16(pv[t][1]);
        pu.s[2] = b16(pv[t][2]); pu.s[3] = b16(pv[t][3]);
        pf[t] = pu.v;
      }
      #pragma unroll
      for (int dt = 0; dt < 4; ++dt)
        #pragma unroll
        for (int t = 0; t < 4; ++t)
          o[qs][dt] = mfma16k(vv[dt].v4[t], pf[t], o[qs][dt]);
    }

    // ---- write buf[cur^1] with tile kv+1 (vmcnt join after compute) ----
    const int nxt = cur ^ 1;
    *(int4*)&Kl[nxt][srow][scol] = kr0; *(int4*)&Kl[nxt][srow][scol + 8] = kr1;
    *(int4*)&Vt[nxt][srow][scol] = vr0; *(int4*)&Vt[nxt][srow][scol + 8] = vr1;
    if (tid < 64) maskf[nxt][tid] = mp ? 1.f : 0.f;
    __syncthreads();
  }

  #pragma unroll
  for (int qs = 0; qs < 2; ++qs) {
    const float rl = 1.f / l[qs];
    unsigned short* dst = AO + ((size_t)(n * SEQ + qb + qs * 16 + lo)) * DM + h * HD + hi * 4;
    #pragma unroll
    for (int dt = 0; dt < 4; ++dt) {
      f32x4 v = o[qs][dt] * rl;
      union { unsigned short s[4]; uint2 u; } p;
      p.s[0] = b16(v[0]); p.s[1] = b16(v[1]); p.s[2] = b16(v[2]); p.s[3] = b16(v[3]);
      *(uint2*)(dst + dt * 16) = p.u;
    }
  }
}

// -------- FC: out = AO @ Wfc^T + bfc, LDS double-buffer --------
__global__ __launch_bounds__(256, 4) void fc_kernel(
    const unsigned short* __restrict__ AO, const float* __restrict__ Wfc,
    const float* __restrict__ bfc, float* __restrict__ out)
{
  __shared__ __align__(16) unsigned short Al[2][64][72];
  __shared__ __align__(16) unsigned short Bl[2][64][72];
  const int tid = threadIdx.x, lane = tid & 63, w = tid >> 6;
  const int hi = lane >> 4, lo = lane & 15;
  const int rb = blockIdx.x * 64, cb = blockIdx.y * 64;
  const int srow = tid >> 2, scol = (tid & 3) * 16;
  const unsigned short* Ab = AO + (size_t)(rb + srow) * DM + scol;
  const float* Bb = Wfc + (size_t)(cb + srow) * DM + scol;

  // prologue: k-block 0 -> buf 0
  {
    int4 a0 = *(const int4*)Ab, a1 = *(const int4*)(Ab + 8);
    float4 w0 = *(const float4*)Bb,       w1 = *(const float4*)(Bb + 4);
    float4 w2 = *(const float4*)(Bb + 8), w3 = *(const float4*)(Bb + 12);
    *(int4*)&Al[0][srow][scol] = a0; *(int4*)&Al[0][srow][scol + 8] = a1;
    *(bf16x8*)&Bl[0][srow][scol]     = cvt8v(w0, w1);
    *(bf16x8*)&Bl[0][srow][scol + 8] = cvt8v(w2, w3);
  }
  __syncthreads();

  f32x4 acc[4];
  #pragma unroll
  for (int t = 0; t < 4; ++t) acc[t] = (f32x4){0.f, 0.f, 0.f, 0.f};

  for (int i = 0; i < 8; ++i) {
    const int cur = i & 1;
    const int kn = ((i + 1) & 7) * 64;
    int4 ar0 = *(const int4*)(Ab + kn), ar1 = *(const int4*)(Ab + kn + 8);
    float4 wr0 = *(const float4*)(Bb + kn),      wr1 = *(const float4*)(Bb + kn + 4);
    float4 wr2 = *(const float4*)(Bb + kn + 8),  wr3 = *(const float4*)(Bb + kn + 12);

    bf16x8 a0 = *(const bf16x8*)&Al[cur][w * 16 + lo][hi * 8];
    bf16x8 a1 = *(const bf16x8*)&Al[cur][w * 16 + lo][32 + hi * 8];
    #pragma unroll
    for (int t = 0; t < 4; ++t) {
      bf16x8 w0 = *(const bf16x8*)&Bl[cur][t * 16 + lo][hi * 8];
      bf16x8 w1 = *(const bf16x8*)&Bl[cur][t * 16 + lo][32 + hi * 8];
      acc[t] = mfma32(a0, w0, acc[t]);
      acc[t] = mfma32(a1, w1, acc[t]);
    }

    const int nxt = cur ^ 1;
    *(int4*)&Al[nxt][srow][scol] = ar0; *(int4*)&Al[nxt][srow][scol + 8] = ar1;
    *(bf16x8*)&Bl[nxt][srow][scol]     = cvt8v(wr0, wr1);
    *(bf16x8*)&Bl[nxt][srow][scol + 8] = cvt8v(wr2, wr3);
    __syncthreads();
  }

  const int rowb = rb + w * 16 + hi * 4;
  #pragma unroll
  for (int t = 0; t < 4; ++t) {
    const float bias = bfc[cb + t * 16 + lo];
    #pragma unroll
    for (int j = 0; j < 4; ++j)
      out[(size_t)(rowb + j) * DM + cb + t * 16 + lo] = acc[t][j] + bias;
  }
}

extern "C" void kernel_launch(void* const* d_in, const int* in_sizes, int n_in,
                              void* d_out, int out_size, void* d_ws, size_t ws_size,
                              hipStream_t stream) {
  const float* value = (const float*)d_in[0];
  const float* key   = (const float*)d_in[1];
  const float* query = (const float*)d_in[2];
  const int*   mask  = (const int*)d_in[3];
  const float* Wv    = (const float*)d_in[4];
  const float* Wk    = (const float*)d_in[5];
  const float* Wq    = (const float*)d_in[6];
  const float* Wfc   = (const float*)d_in[7];
  const float* bfc   = (const float*)d_in[8];
  float* out = (float*)d_out;

  const size_t per = (size_t)N_B * NH * SEQ * HD;  // 4,194,304 elems; 4 bufs = 32 MiB exactly
  unsigned short* Qp = (unsigned short*)d_ws;
  unsigned short* Kp = Qp + per;
  unsigned short* Vp = Kp + per;
  unsigned short* AO = Vp + per;

  proj_kernel<<<dim3(SEQ / 64, N_B * NH, 3), 256, 0, stream>>>(
      query, key, value, Wq, Wk, Wv, Qp, Kp, Vp);
  attn_kernel<<<dim3(SEQ / 128, N_B * NH), 256, 0, stream>>>(Qp, Kp, Vp, mask, AO);
  fc_kernel<<<dim3(N_B * SEQ / 64, DM / 64), 256, 0, stream>>>(AO, Wfc, bfc, out);
}